// Round 2
// baseline (684.267 us; speedup 1.0000x reference)
//
#include <hip/hip_runtime.h>
#include <hip/hip_bf16.h>

// ---------- types / helpers ----------
typedef __attribute__((ext_vector_type(8))) short bf16x8;
typedef __attribute__((ext_vector_type(4))) float f32x4;

__device__ __forceinline__ unsigned short f2b(float f){
  union { float f; unsigned int u; } v; v.f = f;
  unsigned int r = (v.u + 0x7FFFu + ((v.u >> 16) & 1u)) >> 16;  // RNE
  return (unsigned short)r;
}
__device__ __forceinline__ float b2f(unsigned short s){
  union { unsigned int u; float f; } v; v.u = ((unsigned int)s) << 16;
  return v.f;
}
__device__ __forceinline__ f32x4 mfma16(bf16x8 a, bf16x8 b, f32x4 c){
  return __builtin_amdgcn_mfma_f32_16x16x32_bf16(a, b, c, 0, 0, 0);
}

// Problem constants: B=2, C=192, big 224x224 (win 14, 196 tok), small 112x112 (win 7, 49 tok),
// 16x16 windows/image, heads=6, hd=32, hidden=768.

// ---------- weight transpose+cast: W[k][n] fp32 -> Wt[n][k] bf16 ----------
// wT elems: qkvT[576][192] @0 ; projT[192][192] @110592 ; fc1T[768][192] @147456 ; fc2T[192][768] @294912
__global__ __launch_bounds__(256) void k_wconv(const float* __restrict__ qkv_w, const float* __restrict__ proj_w,
                                               const float* __restrict__ fc1_w, const float* __restrict__ fc2_w,
                                               unsigned short* __restrict__ wT){
  int i = blockIdx.x*256 + threadIdx.x;
  if (i < 110592){                       // qkv_w [192][576]
    int k = i / 576, n = i - k*576;
    wT[n*192 + k] = f2b(qkv_w[i]);
  } else if (i < 147456){                // proj_w [192][192]
    int j = i - 110592; int k = j / 192, n = j - k*192;
    wT[110592 + n*192 + k] = f2b(proj_w[j]);
  } else if (i < 294912){                // fc1_w [192][768]
    int j = i - 147456; int k = j / 768, n = j - k*768;
    wT[147456 + n*192 + k] = f2b(fc1_w[j]);
  } else {                               // fc2_w [768][192]
    int j = i - 294912; int k = j / 192, n = j - k*192;
    wT[294912 + n*768 + k] = f2b(fc2_w[j]);
  }
}

// ---------- LayerNorm over C=192 of NCHW input, write bf16 tokens WINDOW-MAJOR ----------
template<int IMG, int WSZ, int NTOK>
__global__ __launch_bounds__(256) void k_ln(const float* __restrict__ xin, const float* __restrict__ nw,
                                            const float* __restrict__ nb, unsigned short* __restrict__ out){
  const int HW = IMG*IMG;
  int tid = threadIdx.x;
  int p = blockIdx.x*256 + tid;
  int b = p / HW, rem = p - b*HW;
  const float* base = xin + (size_t)b*192*HW + rem;
  float s = 0.f, s2 = 0.f;
  for (int c = 0; c < 192; c++){ float v = base[(size_t)c*HW]; s += v; s2 += v*v; }
  float mu = s*(1.f/192.f);
  float var = s2*(1.f/192.f) - mu*mu;
  float rs = rsqrtf(var + 1e-5f);
  int y = rem / IMG, xx = rem - y*IMG;
  int wy = y / WSZ, iy = y - wy*WSZ, wx = xx / WSZ, ix = xx - wx*WSZ;
  int t = ((b*16 + wy)*16 + wx)*NTOK + iy*WSZ + ix;
  __shared__ int srow[256];
  __shared__ unsigned short tile[256][66];
  srow[tid] = t*192;
  int lane = tid & 63, w = tid >> 6;
  for (int c0 = 0; c0 < 192; c0 += 64){
    for (int j = 0; j < 64; j++){
      int c = c0 + j;
      float v = base[(size_t)c*HW];
      tile[tid][j] = f2b((v - mu)*rs*nw[c] + nb[c]);
    }
    __syncthreads();
    for (int i = 0; i < 64; i++){
      int pix = w*64 + i;                 // wave writes one token's 64-ch run (128B coalesced)
      out[srow[pix] + c0 + lane] = tile[pix][lane];
    }
    __syncthreads();
  }
}

// ---------- GEMM: C[M][Nstride] (bf16, +bias) = A[M][192] @ Bt[n][192]^T. BM=64, N-chunk=192 ----------
__global__ __launch_bounds__(256) void k_gemm_full(const unsigned short* A, const unsigned short* Bt,
                                                   const float* __restrict__ bias, unsigned short* C, int Nstride){
  int m0 = blockIdx.x * 64;
  int nbase = blockIdx.y * 192;
  int tid = threadIdx.x, lane = tid & 63, w = tid >> 6;
  int wm = w & 1, wn = w >> 1;
  int r16 = lane & 15, g = lane >> 4, kk8 = g*8;
  __shared__ __align__(16) unsigned short Al[64][40];
  __shared__ __align__(16) unsigned short Bl[192][40];
  f32x4 acc[2][6];
  const f32x4 zz = {0.f,0.f,0.f,0.f};
  for (int a_ = 0; a_ < 2; a_++) for (int b_ = 0; b_ < 6; b_++) acc[a_][b_] = zz;
  int srow = tid >> 2, sseg = (tid & 3)*8;
  for (int k0 = 0; k0 < 192; k0 += 32){
    *(bf16x8*)&Al[srow][sseg] = *(const bf16x8*)&A[(size_t)(m0 + srow)*192 + k0 + sseg];
    for (int s = 0; s < 3; s++){
      int rr = srow + 64*s;
      *(bf16x8*)&Bl[rr][sseg] = *(const bf16x8*)&Bt[(size_t)(nbase + rr)*192 + k0 + sseg];
    }
    __syncthreads();
    bf16x8 a0 = *(bf16x8*)&Al[wm*32 + r16][kk8];
    bf16x8 a1 = *(bf16x8*)&Al[wm*32 + 16 + r16][kk8];
    for (int nj = 0; nj < 6; nj++){
      bf16x8 bb = *(bf16x8*)&Bl[wn*96 + nj*16 + r16][kk8];
      acc[0][nj] = mfma16(a0, bb, acc[0][nj]);
      acc[1][nj] = mfma16(a1, bb, acc[1][nj]);
    }
    __syncthreads();
  }
  for (int mi = 0; mi < 2; mi++) for (int nj = 0; nj < 6; nj++){
    int n = wn*96 + nj*16 + r16;
    float bv = bias[nbase + n];
    for (int r = 0; r < 4; r++){
      int m = m0 + wm*32 + mi*16 + g*4 + r;
      C[(size_t)m*Nstride + nbase + n] = f2b(acc[mi][nj][r] + bv);
    }
  }
}

// ---------- proj + bias + shortcut + window-reverse: 64 pixel-consecutive tokens/block, NCHW fp32 out ----------
__global__ __launch_bounds__(256) void k_proj_res(const unsigned short* __restrict__ A,
                                                  const unsigned short* __restrict__ Bt,
                                                  const float* __restrict__ bias,
                                                  const float* __restrict__ big, float* __restrict__ xout){
  int pix0 = blockIdx.x * 64;
  int b = pix0 / 50176, rem0 = pix0 - b*50176;
  int tid = threadIdx.x, lane = tid & 63, w = tid >> 6;
  int wm = w & 1, wn = w >> 1;
  int r16 = lane & 15, g = lane >> 4, kk8 = g*8;
  __shared__ int tok[64];
  __shared__ __align__(16) char smem[49664];           // union: {Al[64][40],Bl[192][40]} | ot[64][193]
  unsigned short (*Al)[40] = (unsigned short (*)[40])smem;
  unsigned short (*Bl)[40] = (unsigned short (*)[40])(smem + 5120);
  float (*ot)[193] = (float (*)[193])smem;
  if (tid < 64){
    int rem = rem0 + tid, y = rem / 224, x = rem - y*224;
    tok[tid] = ((b*16 + y/14)*16 + x/14)*196 + (y%14)*14 + (x%14);
  }
  __syncthreads();
  int srow = tid >> 2, sseg = (tid & 3)*8;
  int myTok = tok[srow];
  f32x4 acc[2][6];
  const f32x4 zz = {0.f,0.f,0.f,0.f};
  for (int a_ = 0; a_ < 2; a_++) for (int b_ = 0; b_ < 6; b_++) acc[a_][b_] = zz;
  for (int k0 = 0; k0 < 192; k0 += 32){
    *(bf16x8*)&Al[srow][sseg] = *(const bf16x8*)&A[(size_t)myTok*192 + k0 + sseg];
    for (int s = 0; s < 3; s++){
      int rr = srow + 64*s;
      *(bf16x8*)&Bl[rr][sseg] = *(const bf16x8*)&Bt[(size_t)rr*192 + k0 + sseg];
    }
    __syncthreads();
    bf16x8 a0 = *(bf16x8*)&Al[wm*32 + r16][kk8];
    bf16x8 a1 = *(bf16x8*)&Al[wm*32 + 16 + r16][kk8];
    for (int nj = 0; nj < 6; nj++){
      bf16x8 bb = *(bf16x8*)&Bl[wn*96 + nj*16 + r16][kk8];
      acc[0][nj] = mfma16(a0, bb, acc[0][nj]);
      acc[1][nj] = mfma16(a1, bb, acc[1][nj]);
    }
    __syncthreads();
  }
  // Al/Bl dead; reuse as fp32 ot[64][193]
  for (int mi = 0; mi < 2; mi++) for (int nj = 0; nj < 6; nj++){
    int n = wn*96 + nj*16 + r16;
    float bv = bias[n];
    for (int r = 0; r < 4; r++)
      ot[wm*32 + mi*16 + g*4 + r][n] = acc[mi][nj][r] + bv;
  }
  __syncthreads();
  for (int j = 0; j < 48; j++){                         // coalesced NCHW read-modify-write (256B runs)
    int flat = j*256 + tid;
    int c = flat >> 6, p = flat & 63;
    size_t addr = ((size_t)b*192 + c)*50176 + rem0 + p;
    xout[addr] = ot[p][c] + big[addr];
  }
}

// ---------- attention: one block per (window, head). In-place output over q. ----------
__global__ __launch_bounds__(256) void k_attn(unsigned short* q, const unsigned short* __restrict__ kv,
                                              const float* __restrict__ rpb){
  int win = blockIdx.x / 6, head = blockIdx.x - win*6;
  int tid = threadIdx.x, lane = tid & 63, w = tid >> 6;
  __shared__ __align__(16) unsigned short ql[208][40];
  __shared__ __align__(16) unsigned short kl[64][40];
  __shared__ __align__(16) unsigned short vt[32][72];
  __shared__ __align__(16) unsigned short plds[4][16][72];
  __shared__ float rb[729];
  float4 z4; z4.x = z4.y = z4.z = z4.w = 0.f;
  {
    float4* a4 = (float4*)&ql[0][0];
    for (int i = tid; i < 1040; i += 256) a4[i] = z4;
    float4* b4 = (float4*)&kl[0][0];
    for (int i = tid; i < 320; i += 256) b4[i] = z4;
    float4* c4 = (float4*)&vt[0][0];
    for (int i = tid; i < 288; i += 256) c4[i] = z4;
  }
  __syncthreads();
  const unsigned short* qbase = q + (size_t)win*196*192 + head*32;
  for (int r4 = tid; r4 < 784; r4 += 256){
    int r = r4 >> 2, seg = (r4 & 3)*8;
    *(bf16x8*)&ql[r][seg] = *(const bf16x8*)&qbase[(size_t)r*192 + seg];
  }
  const unsigned short* kbase = kv + (size_t)win*49*384 + head*32;
  if (tid < 196){
    int r = tid >> 2, seg = (tid & 3)*8;
    *(bf16x8*)&kl[r][seg] = *(const bf16x8*)&kbase[(size_t)r*384 + seg];
  }
  const unsigned short* vbase = kbase + 192;
  for (int md = tid; md < 392; md += 256){
    int m = md >> 3, d0 = (md & 7)*4;
    const unsigned short* src = vbase + (size_t)m*384 + d0;
    vt[d0][m] = src[0]; vt[d0+1][m] = src[1]; vt[d0+2][m] = src[2]; vt[d0+3][m] = src[3];
  }
  for (int i = tid; i < 729; i += 256) rb[i] = rpb[i*6 + head];
  __syncthreads();
  int r16 = lane & 15, g = lane >> 4, kk8 = g*8;
  const f32x4 zz = {0.f,0.f,0.f,0.f};
  unsigned short* obase = q + (size_t)win*196*192 + head*32;
  for (int mt = w; mt < 13; mt += 4){
    bf16x8 a = *(bf16x8*)&ql[mt*16 + r16][kk8];
    f32x4 s[4];
    for (int nt = 0; nt < 4; nt++){
      bf16x8 bb = *(bf16x8*)&kl[nt*16 + r16][kk8];
      s[nt] = mfma16(a, bb, zz);
    }
    int nb0 = mt*16 + g*4;
    for (int nt = 0; nt < 4; nt++){
      int m = nt*16 + r16;
      if (m < 49){
        int jy = m / 7, jx = m - jy*7;
        for (int r = 0; r < 4; r++){
          int n = nb0 + r; if (n > 195) n = 195;   // clamp pad rows (values unused)
          int iy = n / 14, ix = n - iy*14;
          s[nt][r] += rb[(iy - jy + 13)*27 + (ix - jx + 13)];
        }
      } else {
        s[nt][0] = -1e30f; s[nt][1] = -1e30f; s[nt][2] = -1e30f; s[nt][3] = -1e30f;
      }
    }
    for (int r = 0; r < 4; r++){
      float mx = fmaxf(fmaxf(s[0][r], s[1][r]), fmaxf(s[2][r], s[3][r]));
      mx = fmaxf(mx, __shfl_xor(mx, 1, 16));
      mx = fmaxf(mx, __shfl_xor(mx, 2, 16));
      mx = fmaxf(mx, __shfl_xor(mx, 4, 16));
      mx = fmaxf(mx, __shfl_xor(mx, 8, 16));
      float sum = 0.f;
      for (int nt = 0; nt < 4; nt++){ float e = __expf(s[nt][r] - mx); s[nt][r] = e; sum += e; }
      sum += __shfl_xor(sum, 1, 16);
      sum += __shfl_xor(sum, 2, 16);
      sum += __shfl_xor(sum, 4, 16);
      sum += __shfl_xor(sum, 8, 16);
      float inv = 1.0f / sum;
      for (int nt = 0; nt < 4; nt++) s[nt][r] *= inv;
    }
    for (int nt = 0; nt < 4; nt++)
      for (int r = 0; r < 4; r++)
        plds[w][g*4 + r][nt*16 + r16] = f2b(s[nt][r]);
    asm volatile("s_waitcnt lgkmcnt(0)" ::: "memory");
    f32x4 o0 = zz, o1 = zz;
    for (int ks = 0; ks < 2; ks++){
      bf16x8 pa = *(bf16x8*)&plds[w][r16][ks*32 + kk8];
      bf16x8 v0 = *(bf16x8*)&vt[r16][ks*32 + kk8];
      bf16x8 v1 = *(bf16x8*)&vt[16 + r16][ks*32 + kk8];
      o0 = mfma16(pa, v0, o0);
      o1 = mfma16(pa, v1, o1);
    }
    for (int r = 0; r < 4; r++){
      int n = nb0 + r;
      if (n < 196){
        obase[(size_t)n*192 + r16]      = f2b(o0[r]);
        obase[(size_t)n*192 + 16 + r16] = f2b(o1[r]);
      }
    }
  }
}

// ---------- fused MLP: LN -> fc1+GELU -> fc2 -> +residual. NCHW fp32 in/out, block owns its 64-pixel slab ----------
__global__ __launch_bounds__(512) void k_mlp(float* xio, const unsigned short* __restrict__ fc1T, const float* __restrict__ b1,
                                             const unsigned short* __restrict__ fc2T, const float* __restrict__ b2,
                                             const float* __restrict__ nw, const float* __restrict__ nb){
  __shared__ __align__(16) unsigned short xv[64][198];
  __shared__ __align__(16) unsigned short xln[64][200];
  __shared__ __align__(16) unsigned short ul[64][72];
  int pix0 = blockIdx.x * 64;
  int b = pix0 / 50176, rem0 = pix0 - b*50176;
  int tid = threadIdx.x, lane = tid & 63, w = tid >> 6;
  float xr[24];                                       // residual x stays fp32 in regs
  for (int i = 0; i < 24; i++){
    int c = i*8 + (tid >> 6), p = tid & 63;
    float v = xio[((size_t)b*192 + c)*50176 + rem0 + p];
    xr[i] = v;
    xv[p][c] = f2b(v);
  }
  __syncthreads();
  { // LN: 8 threads per token row
    int row = tid >> 3, sub = tid & 7;
    float s = 0.f, s2 = 0.f;
    for (int j = 0; j < 24; j++){ float v = b2f(xv[row][sub*24 + j]); s += v; s2 += v*v; }
    s  += __shfl_xor(s, 1, 8);  s2 += __shfl_xor(s2, 1, 8);
    s  += __shfl_xor(s, 2, 8);  s2 += __shfl_xor(s2, 2, 8);
    s  += __shfl_xor(s, 4, 8);  s2 += __shfl_xor(s2, 4, 8);
    float mu = s*(1.f/192.f), var = s2*(1.f/192.f) - mu*mu, rs = rsqrtf(var + 1e-5f);
    for (int j = 0; j < 24; j++){
      int c = sub*24 + j;
      float v = b2f(xv[row][c]);
      xln[row][c] = f2b((v - mu)*rs*nw[c] + nb[c]);
    }
  }
  __syncthreads();
  int wm = w >> 2, wn = w & 3;
  int r16 = lane & 15, g = lane >> 4, kk8 = g*8;
  const f32x4 zz = {0.f,0.f,0.f,0.f};
  f32x4 acc2[2][3];
  acc2[0][0]=zz; acc2[0][1]=zz; acc2[0][2]=zz; acc2[1][0]=zz; acc2[1][1]=zz; acc2[1][2]=zz;
  for (int kh = 0; kh < 12; kh++){
    f32x4 u0 = zz, u1 = zz;
    int nc = kh*64 + wn*16 + r16;
    for (int ks = 0; ks < 6; ks++){
      bf16x8 bb = *(const bf16x8*)&fc1T[(size_t)nc*192 + ks*32 + kk8];
      bf16x8 a0 = *(bf16x8*)&xln[wm*32 + r16][ks*32 + kk8];
      bf16x8 a1 = *(bf16x8*)&xln[wm*32 + 16 + r16][ks*32 + kk8];
      u0 = mfma16(a0, bb, u0);
      u1 = mfma16(a1, bb, u1);
    }
    float bias1 = b1[nc];
    for (int r = 0; r < 4; r++){
      float uu = u0[r] + bias1;
      ul[wm*32 + g*4 + r][wn*16 + r16]      = f2b(0.5f*uu*(1.f + erff(uu*0.70710678f)));
      float vv = u1[r] + bias1;
      ul[wm*32 + 16 + g*4 + r][wn*16 + r16] = f2b(0.5f*vv*(1.f + erff(vv*0.70710678f)));
    }
    __syncthreads();
    for (int ks = 0; ks < 2; ks++){
      bf16x8 a0 = *(bf16x8*)&ul[wm*32 + r16][ks*32 + kk8];
      bf16x8 a1 = *(bf16x8*)&ul[wm*32 + 16 + r16][ks*32 + kk8];
      for (int j = 0; j < 3; j++){
        int n2 = wn*16 + j*64 + r16;
        bf16x8 bb = *(const bf16x8*)&fc2T[(size_t)n2*768 + kh*64 + ks*32 + kk8];
        acc2[0][j] = mfma16(a0, bb, acc2[0][j]);
        acc2[1][j] = mfma16(a1, bb, acc2[1][j]);
      }
    }
    __syncthreads();
  }
  // h (bf16) into xv (xv dead after LN), then fp32 residual from regs
  for (int mi = 0; mi < 2; mi++) for (int j = 0; j < 3; j++){
    int c = wn*16 + j*64 + r16;
    float bias2 = b2[c];
    for (int r = 0; r < 4; r++){
      int t = wm*32 + mi*16 + g*4 + r;
      xv[t][c] = f2b(acc2[mi][j][r] + bias2);
    }
  }
  __syncthreads();
  for (int i = 0; i < 24; i++){
    int c = i*8 + (tid >> 6), p = tid & 63;
    xio[((size_t)b*192 + c)*50176 + rem0 + p] = xr[i] + b2f(xv[p][c]);
  }
}

// ---------- launcher ----------
extern "C" void kernel_launch(void* const* d_in, const int* in_sizes, int n_in,
                              void* d_out, int out_size, void* d_ws, size_t ws_size,
                              hipStream_t stream){
  (void)in_sizes; (void)n_in; (void)out_size; (void)ws_size;
  const float* bigx   = (const float*)d_in[0];
  const float* smx    = (const float*)d_in[1];
  const float* nw     = (const float*)d_in[2];
  const float* nb_    = (const float*)d_in[3];
  const float* qkv_w  = (const float*)d_in[4];
  const float* qkv_b  = (const float*)d_in[5];
  const float* rpb    = (const float*)d_in[6];
  const float* proj_w = (const float*)d_in[7];
  const float* proj_b = (const float*)d_in[8];
  const float* fc1_w  = (const float*)d_in[9];
  const float* fc1_b  = (const float*)d_in[10];
  const float* fc2_w  = (const float*)d_in[11];
  const float* fc2_b  = (const float*)d_in[12];

  char* ws = (char*)d_ws;
  unsigned short* wT  = (unsigned short*)ws;                    // 442368 elems (884736 B)
  unsigned short* bxn = (unsigned short*)(ws + 884736);         // 100352*192 bf16 (LN big -> Q -> attn out)
  unsigned short* xsn = (unsigned short*)(ws + 39419904);       // 25088*192 bf16
  unsigned short* kvb = (unsigned short*)(ws + 49053696);       // 25088*384 bf16
  float* xo = (float*)d_out;                                    // residual stream x, NCHW fp32

  k_wconv<<<1728, 256, 0, stream>>>(qkv_w, proj_w, fc1_w, fc2_w, wT);
  k_ln<224,14,196><<<392, 256, 0, stream>>>(bigx, nw, nb_, bxn);
  k_ln<112,7,49><<<98, 256, 0, stream>>>(smx, nw, nb_, xsn);
  // Q = bxn @ Wq + bq (in-place: each block reads only its own 64 rows before writing them)
  k_gemm_full<<<dim3(1568,1), 256, 0, stream>>>(bxn, wT, qkv_b, bxn, 192);
  // KV = xsn @ Wkv + bkv
  k_gemm_full<<<dim3(392,2), 256, 0, stream>>>(xsn, wT + 36864, qkv_b + 192, kvb, 384);
  // attention (in-place over q; disjoint row x head-col regions per block)
  k_attn<<<3072, 256, 0, stream>>>(bxn, kvb, rpb);
  // proj + bias + shortcut + window-reverse -> x (NCHW fp32 in d_out)
  k_proj_res<<<1568, 256, 0, stream>>>(bxn, wT + 110592, proj_b, bigx, xo);
  // LN -> MLP -> +residual (each block owns its 64-pixel NCHW slab; race-free)
  k_mlp<<<1568, 512, 0, stream>>>(xo, wT + 147456, fc1_b, wT + 294912, fc2_b, nw, nb_);
}

// Round 3
// 668.882 us; speedup vs baseline: 1.0230x; 1.0230x over previous
//
#include <hip/hip_runtime.h>
#include <hip/hip_bf16.h>

// ---------- types / helpers ----------
typedef __attribute__((ext_vector_type(8))) short bf16x8;
typedef __attribute__((ext_vector_type(4))) float f32x4;

__device__ __forceinline__ unsigned short f2b(float f){
  union { float f; unsigned int u; } v; v.f = f;
  unsigned int r = (v.u + 0x7FFFu + ((v.u >> 16) & 1u)) >> 16;  // RNE
  return (unsigned short)r;
}
__device__ __forceinline__ float b2f(unsigned short s){
  union { unsigned int u; float f; } v; v.u = ((unsigned int)s) << 16;
  return v.f;
}
__device__ __forceinline__ f32x4 mfma16(bf16x8 a, bf16x8 b, f32x4 c){
  return __builtin_amdgcn_mfma_f32_16x16x32_bf16(a, b, c, 0, 0, 0);
}

// Problem constants: B=2, C=192, big 224x224 (win 14, 196 tok), small 112x112 (win 7, 49 tok),
// 16x16 windows/image, heads=6, hd=32, hidden=768.

// ---------- weight transpose+cast: W[k][n] fp32 -> Wt[n][k] bf16 ----------
// wT elems: qkvT[576][192] @0 ; projT[192][192] @110592 ; fc1T[768][192] @147456 ; fc2T[192][768] @294912
__global__ __launch_bounds__(256) void k_wconv(const float* __restrict__ qkv_w, const float* __restrict__ proj_w,
                                               const float* __restrict__ fc1_w, const float* __restrict__ fc2_w,
                                               unsigned short* __restrict__ wT){
  int i = blockIdx.x*256 + threadIdx.x;
  if (i < 110592){                       // qkv_w [192][576]
    int k = i / 576, n = i - k*576;
    wT[n*192 + k] = f2b(qkv_w[i]);
  } else if (i < 147456){                // proj_w [192][192]
    int j = i - 110592; int k = j / 192, n = j - k*192;
    wT[110592 + n*192 + k] = f2b(proj_w[j]);
  } else if (i < 294912){                // fc1_w [192][768]
    int j = i - 147456; int k = j / 768, n = j - k*768;
    wT[147456 + n*192 + k] = f2b(fc1_w[j]);
  } else {                               // fc2_w [768][192]
    int j = i - 294912; int k = j / 192, n = j - k*192;
    wT[294912 + n*768 + k] = f2b(fc2_w[j]);
  }
}

// ---------- LayerNorm over C=192 of NCHW input, write bf16 tokens WINDOW-MAJOR ----------
template<int IMG, int WSZ, int NTOK>
__global__ __launch_bounds__(256) void k_ln(const float* __restrict__ xin, const float* __restrict__ nw,
                                            const float* __restrict__ nb, unsigned short* __restrict__ out){
  const int HW = IMG*IMG;
  int tid = threadIdx.x;
  int p = blockIdx.x*256 + tid;
  int b = p / HW, rem = p - b*HW;
  const float* base = xin + (size_t)b*192*HW + rem;
  float s = 0.f, s2 = 0.f;
  for (int c = 0; c < 192; c++){ float v = base[(size_t)c*HW]; s += v; s2 += v*v; }
  float mu = s*(1.f/192.f);
  float var = s2*(1.f/192.f) - mu*mu;
  float rs = rsqrtf(var + 1e-5f);
  int y = rem / IMG, xx = rem - y*IMG;
  int wy = y / WSZ, iy = y - wy*WSZ, wx = xx / WSZ, ix = xx - wx*WSZ;
  int t = ((b*16 + wy)*16 + wx)*NTOK + iy*WSZ + ix;
  __shared__ int srow[256];
  __shared__ unsigned short tile[256][66];
  srow[tid] = t*192;
  int lane = tid & 63, w = tid >> 6;
  for (int c0 = 0; c0 < 192; c0 += 64){
    for (int j = 0; j < 64; j++){
      int c = c0 + j;
      float v = base[(size_t)c*HW];
      tile[tid][j] = f2b((v - mu)*rs*nw[c] + nb[c]);
    }
    __syncthreads();
    for (int i = 0; i < 64; i++){
      int pix = w*64 + i;                 // wave writes one token's 64-ch run (128B coalesced)
      out[srow[pix] + c0 + lane] = tile[pix][lane];
    }
    __syncthreads();
  }
}

// ---------- GEMM: C[M][Nstride] (bf16, +bias) = A[M][192] @ Bt[n][192]^T. BM=64, N-chunk=192 ----------
__global__ __launch_bounds__(256) void k_gemm_full(const unsigned short* A, const unsigned short* Bt,
                                                   const float* __restrict__ bias, unsigned short* C, int Nstride){
  int m0 = blockIdx.x * 64;
  int nbase = blockIdx.y * 192;
  int tid = threadIdx.x, lane = tid & 63, w = tid >> 6;
  int wm = w & 1, wn = w >> 1;
  int r16 = lane & 15, g = lane >> 4, kk8 = g*8;
  __shared__ __align__(16) unsigned short Al[64][40];
  __shared__ __align__(16) unsigned short Bl[192][40];
  f32x4 acc[2][6];
  const f32x4 zz = {0.f,0.f,0.f,0.f};
  for (int a_ = 0; a_ < 2; a_++) for (int b_ = 0; b_ < 6; b_++) acc[a_][b_] = zz;
  int srow = tid >> 2, sseg = (tid & 3)*8;
  for (int k0 = 0; k0 < 192; k0 += 32){
    *(bf16x8*)&Al[srow][sseg] = *(const bf16x8*)&A[(size_t)(m0 + srow)*192 + k0 + sseg];
    for (int s = 0; s < 3; s++){
      int rr = srow + 64*s;
      *(bf16x8*)&Bl[rr][sseg] = *(const bf16x8*)&Bt[(size_t)(nbase + rr)*192 + k0 + sseg];
    }
    __syncthreads();
    bf16x8 a0 = *(bf16x8*)&Al[wm*32 + r16][kk8];
    bf16x8 a1 = *(bf16x8*)&Al[wm*32 + 16 + r16][kk8];
    for (int nj = 0; nj < 6; nj++){
      bf16x8 bb = *(bf16x8*)&Bl[wn*96 + nj*16 + r16][kk8];
      acc[0][nj] = mfma16(a0, bb, acc[0][nj]);
      acc[1][nj] = mfma16(a1, bb, acc[1][nj]);
    }
    __syncthreads();
  }
  for (int mi = 0; mi < 2; mi++) for (int nj = 0; nj < 6; nj++){
    int n = wn*96 + nj*16 + r16;
    float bv = bias[nbase + n];
    for (int r = 0; r < 4; r++){
      int m = m0 + wm*32 + mi*16 + g*4 + r;
      C[(size_t)m*Nstride + nbase + n] = f2b(acc[mi][nj][r] + bv);
    }
  }
}

// ---------- proj + bias + shortcut + window-reverse: 64 pixel-consecutive tokens/block, NCHW fp32 out ----------
__global__ __launch_bounds__(256) void k_proj_res(const unsigned short* __restrict__ A,
                                                  const unsigned short* __restrict__ Bt,
                                                  const float* __restrict__ bias,
                                                  const float* __restrict__ big, float* __restrict__ xout){
  int pix0 = blockIdx.x * 64;
  int b = pix0 / 50176, rem0 = pix0 - b*50176;
  int tid = threadIdx.x, lane = tid & 63, w = tid >> 6;
  int wm = w & 1, wn = w >> 1;
  int r16 = lane & 15, g = lane >> 4, kk8 = g*8;
  __shared__ int tok[64];
  __shared__ __align__(16) char smem[49664];           // union: {Al[64][40],Bl[192][40]} | ot[64][193]
  unsigned short (*Al)[40] = (unsigned short (*)[40])smem;
  unsigned short (*Bl)[40] = (unsigned short (*)[40])(smem + 5120);
  float (*ot)[193] = (float (*)[193])smem;
  if (tid < 64){
    int rem = rem0 + tid, y = rem / 224, x = rem - y*224;
    tok[tid] = ((b*16 + y/14)*16 + x/14)*196 + (y%14)*14 + (x%14);
  }
  __syncthreads();
  int srow = tid >> 2, sseg = (tid & 3)*8;
  int myTok = tok[srow];
  f32x4 acc[2][6];
  const f32x4 zz = {0.f,0.f,0.f,0.f};
  for (int a_ = 0; a_ < 2; a_++) for (int b_ = 0; b_ < 6; b_++) acc[a_][b_] = zz;
  for (int k0 = 0; k0 < 192; k0 += 32){
    *(bf16x8*)&Al[srow][sseg] = *(const bf16x8*)&A[(size_t)myTok*192 + k0 + sseg];
    for (int s = 0; s < 3; s++){
      int rr = srow + 64*s;
      *(bf16x8*)&Bl[rr][sseg] = *(const bf16x8*)&Bt[(size_t)rr*192 + k0 + sseg];
    }
    __syncthreads();
    bf16x8 a0 = *(bf16x8*)&Al[wm*32 + r16][kk8];
    bf16x8 a1 = *(bf16x8*)&Al[wm*32 + 16 + r16][kk8];
    for (int nj = 0; nj < 6; nj++){
      bf16x8 bb = *(bf16x8*)&Bl[wn*96 + nj*16 + r16][kk8];
      acc[0][nj] = mfma16(a0, bb, acc[0][nj]);
      acc[1][nj] = mfma16(a1, bb, acc[1][nj]);
    }
    __syncthreads();
  }
  // Al/Bl dead; reuse as fp32 ot[64][193]
  for (int mi = 0; mi < 2; mi++) for (int nj = 0; nj < 6; nj++){
    int n = wn*96 + nj*16 + r16;
    float bv = bias[n];
    for (int r = 0; r < 4; r++)
      ot[wm*32 + mi*16 + g*4 + r][n] = acc[mi][nj][r] + bv;
  }
  __syncthreads();
  for (int j = 0; j < 48; j++){                         // coalesced NCHW read-modify-write (256B runs)
    int flat = j*256 + tid;
    int c = flat >> 6, p = flat & 63;
    size_t addr = ((size_t)b*192 + c)*50176 + rem0 + p;
    xout[addr] = ot[p][c] + big[addr];
  }
}

// ---------- attention: one block per (window, head). In-place output over q. ----------
__global__ __launch_bounds__(256) void k_attn(unsigned short* q, const unsigned short* __restrict__ kv,
                                              const float* __restrict__ rpb){
  int win = blockIdx.x / 6, head = blockIdx.x - win*6;
  int tid = threadIdx.x, lane = tid & 63, w = tid >> 6;
  __shared__ __align__(16) unsigned short ql[208][40];
  __shared__ __align__(16) unsigned short kl[64][40];
  __shared__ __align__(16) unsigned short vt[32][72];
  __shared__ __align__(16) unsigned short plds[4][16][72];
  __shared__ float rb[729];
  float4 z4; z4.x = z4.y = z4.z = z4.w = 0.f;
  {
    float4* a4 = (float4*)&ql[0][0];
    for (int i = tid; i < 1040; i += 256) a4[i] = z4;
    float4* b4 = (float4*)&kl[0][0];
    for (int i = tid; i < 320; i += 256) b4[i] = z4;
    float4* c4 = (float4*)&vt[0][0];
    for (int i = tid; i < 288; i += 256) c4[i] = z4;
  }
  __syncthreads();
  const unsigned short* qbase = q + (size_t)win*196*192 + head*32;
  for (int r4 = tid; r4 < 784; r4 += 256){
    int r = r4 >> 2, seg = (r4 & 3)*8;
    *(bf16x8*)&ql[r][seg] = *(const bf16x8*)&qbase[(size_t)r*192 + seg];
  }
  const unsigned short* kbase = kv + (size_t)win*49*384 + head*32;
  if (tid < 196){
    int r = tid >> 2, seg = (tid & 3)*8;
    *(bf16x8*)&kl[r][seg] = *(const bf16x8*)&kbase[(size_t)r*384 + seg];
  }
  const unsigned short* vbase = kbase + 192;
  for (int md = tid; md < 392; md += 256){
    int m = md >> 3, d0 = (md & 7)*4;
    const unsigned short* src = vbase + (size_t)m*384 + d0;
    vt[d0][m] = src[0]; vt[d0+1][m] = src[1]; vt[d0+2][m] = src[2]; vt[d0+3][m] = src[3];
  }
  for (int i = tid; i < 729; i += 256) rb[i] = rpb[i*6 + head];
  __syncthreads();
  int r16 = lane & 15, g = lane >> 4, kk8 = g*8;
  const f32x4 zz = {0.f,0.f,0.f,0.f};
  unsigned short* obase = q + (size_t)win*196*192 + head*32;
  for (int mt = w; mt < 13; mt += 4){
    bf16x8 a = *(bf16x8*)&ql[mt*16 + r16][kk8];
    f32x4 s[4];
    for (int nt = 0; nt < 4; nt++){
      bf16x8 bb = *(bf16x8*)&kl[nt*16 + r16][kk8];
      s[nt] = mfma16(a, bb, zz);
    }
    int nb0 = mt*16 + g*4;
    for (int nt = 0; nt < 4; nt++){
      int m = nt*16 + r16;
      if (m < 49){
        int jy = m / 7, jx = m - jy*7;
        for (int r = 0; r < 4; r++){
          int n = nb0 + r; if (n > 195) n = 195;   // clamp pad rows (values unused)
          int iy = n / 14, ix = n - iy*14;
          s[nt][r] += rb[(iy - jy + 13)*27 + (ix - jx + 13)];
        }
      } else {
        s[nt][0] = -1e30f; s[nt][1] = -1e30f; s[nt][2] = -1e30f; s[nt][3] = -1e30f;
      }
    }
    for (int r = 0; r < 4; r++){
      float mx = fmaxf(fmaxf(s[0][r], s[1][r]), fmaxf(s[2][r], s[3][r]));
      mx = fmaxf(mx, __shfl_xor(mx, 1, 16));
      mx = fmaxf(mx, __shfl_xor(mx, 2, 16));
      mx = fmaxf(mx, __shfl_xor(mx, 4, 16));
      mx = fmaxf(mx, __shfl_xor(mx, 8, 16));
      float sum = 0.f;
      for (int nt = 0; nt < 4; nt++){ float e = __expf(s[nt][r] - mx); s[nt][r] = e; sum += e; }
      sum += __shfl_xor(sum, 1, 16);
      sum += __shfl_xor(sum, 2, 16);
      sum += __shfl_xor(sum, 4, 16);
      sum += __shfl_xor(sum, 8, 16);
      float inv = 1.0f / sum;
      for (int nt = 0; nt < 4; nt++) s[nt][r] *= inv;
    }
    for (int nt = 0; nt < 4; nt++)
      for (int r = 0; r < 4; r++)
        plds[w][g*4 + r][nt*16 + r16] = f2b(s[nt][r]);
    asm volatile("s_waitcnt lgkmcnt(0)" ::: "memory");
    f32x4 o0 = zz, o1 = zz;
    for (int ks = 0; ks < 2; ks++){
      bf16x8 pa = *(bf16x8*)&plds[w][r16][ks*32 + kk8];
      bf16x8 v0 = *(bf16x8*)&vt[r16][ks*32 + kk8];
      bf16x8 v1 = *(bf16x8*)&vt[16 + r16][ks*32 + kk8];
      o0 = mfma16(pa, v0, o0);
      o1 = mfma16(pa, v1, o1);
    }
    for (int r = 0; r < 4; r++){
      int n = nb0 + r;
      if (n < 196){
        obase[(size_t)n*192 + r16]      = f2b(o0[r]);
        obase[(size_t)n*192 + 16 + r16] = f2b(o1[r]);
      }
    }
  }
}

// ---------- fused MLP: LN -> fc1+GELU -> fc2 -> +residual. NCHW fp32 in/out, block owns its 64-pixel slab ----------
// Round-3 restructure: in-place LN (no xln), double-buffered ul, ONE barrier per kh chunk,
// fc1(kh+1) interleaved with fc2(kh), split fc1 accumulation chains.
__global__ __launch_bounds__(512, 5) void k_mlp(float* xio, const unsigned short* __restrict__ fc1T, const float* __restrict__ b1,
                                                const unsigned short* __restrict__ fc2T, const float* __restrict__ b2,
                                                const float* __restrict__ nw, const float* __restrict__ nb){
  __shared__ __align__(16) unsigned short xv[64][200];   // x bf16, then LN(x) in place, then h output
  __shared__ __align__(16) unsigned short ul[2][64][72]; // GELU(fc1) double buffer
  int pix0 = blockIdx.x * 64;
  int b = pix0 / 50176, rem0 = pix0 - b*50176;
  int tid = threadIdx.x, lane = tid & 63, w = tid >> 6;
  for (int i = 0; i < 24; i++){
    int c = i*8 + (tid >> 6), p = tid & 63;
    xv[p][c] = f2b(xio[((size_t)b*192 + c)*50176 + rem0 + p]);
  }
  __syncthreads();
  { // LN in place: 8 threads per token row, each owns a 24-col segment
    int row = tid >> 3, sub = tid & 7;
    float s = 0.f, s2 = 0.f;
    for (int j = 0; j < 24; j++){ float v = b2f(xv[row][sub*24 + j]); s += v; s2 += v*v; }
    s  += __shfl_xor(s, 1, 8);  s2 += __shfl_xor(s2, 1, 8);
    s  += __shfl_xor(s, 2, 8);  s2 += __shfl_xor(s2, 2, 8);
    s  += __shfl_xor(s, 4, 8);  s2 += __shfl_xor(s2, 4, 8);
    float mu = s*(1.f/192.f), var = s2*(1.f/192.f) - mu*mu, rs = rsqrtf(var + 1e-5f);
    for (int j = 0; j < 24; j++){
      int c = sub*24 + j;
      float v = b2f(xv[row][c]);
      xv[row][c] = f2b((v - mu)*rs*nw[c] + nb[c]);
    }
  }
  __syncthreads();
  int wm = w >> 2, wn = w & 3;
  int r16 = lane & 15, g = lane >> 4, kk8 = g*8;
  const f32x4 zz = {0.f,0.f,0.f,0.f};

#define FC1_CHUNK(KH, BUF)                                                          \
  {                                                                                 \
    f32x4 u0a = zz, u0b = zz, u1a = zz, u1b = zz;                                   \
    int nc = (KH)*64 + wn*16 + r16;                                                 \
    for (int ks = 0; ks < 3; ks++){                                                 \
      bf16x8 bb0 = *(const bf16x8*)&fc1T[(size_t)nc*192 + ks*32 + kk8];             \
      bf16x8 bb1 = *(const bf16x8*)&fc1T[(size_t)nc*192 + (ks+3)*32 + kk8];         \
      bf16x8 a0 = *(bf16x8*)&xv[wm*32 + r16][ks*32 + kk8];                          \
      bf16x8 a1 = *(bf16x8*)&xv[wm*32 + 16 + r16][ks*32 + kk8];                     \
      bf16x8 a0b = *(bf16x8*)&xv[wm*32 + r16][(ks+3)*32 + kk8];                     \
      bf16x8 a1b = *(bf16x8*)&xv[wm*32 + 16 + r16][(ks+3)*32 + kk8];                \
      u0a = mfma16(a0, bb0, u0a);  u1a = mfma16(a1, bb0, u1a);                      \
      u0b = mfma16(a0b, bb1, u0b); u1b = mfma16(a1b, bb1, u1b);                     \
    }                                                                               \
    float b1v = b1[nc];                                                             \
    for (int r = 0; r < 4; r++){                                                    \
      float uu = u0a[r] + u0b[r] + b1v;                                             \
      ul[BUF][wm*32 + g*4 + r][wn*16 + r16]      = f2b(0.5f*uu*(1.f + erff(uu*0.70710678f))); \
      float vv = u1a[r] + u1b[r] + b1v;                                             \
      ul[BUF][wm*32 + 16 + g*4 + r][wn*16 + r16] = f2b(0.5f*vv*(1.f + erff(vv*0.70710678f))); \
    }                                                                               \
  }

  f32x4 acc2[2][3];
  acc2[0][0]=zz; acc2[0][1]=zz; acc2[0][2]=zz; acc2[1][0]=zz; acc2[1][1]=zz; acc2[1][2]=zz;
  FC1_CHUNK(0, 0)
  __syncthreads();
  for (int kh = 0; kh < 12; kh++){
    int cur = kh & 1;
    if (kh < 11){ FC1_CHUNK(kh+1, cur^1) }          // produce next chunk's GELU(u)
    for (int ks = 0; ks < 2; ks++){                  // consume current chunk
      bf16x8 a0 = *(bf16x8*)&ul[cur][wm*32 + r16][ks*32 + kk8];
      bf16x8 a1 = *(bf16x8*)&ul[cur][wm*32 + 16 + r16][ks*32 + kk8];
      for (int j = 0; j < 3; j++){
        int n2 = wn*16 + j*64 + r16;
        bf16x8 bb = *(const bf16x8*)&fc2T[(size_t)n2*768 + kh*64 + ks*32 + kk8];
        acc2[0][j] = mfma16(a0, bb, acc2[0][j]);
        acc2[1][j] = mfma16(a1, bb, acc2[1][j]);
      }
    }
    __syncthreads();
  }
#undef FC1_CHUNK
  // h (bf16) into xv (dead after last fc1), then residual re-read from global
  for (int mi = 0; mi < 2; mi++) for (int j = 0; j < 3; j++){
    int c = wn*16 + j*64 + r16;
    float bias2 = b2[c];
    for (int r = 0; r < 4; r++){
      int t = wm*32 + mi*16 + g*4 + r;
      xv[t][c] = f2b(acc2[mi][j][r] + bias2);
    }
  }
  __syncthreads();
  for (int i = 0; i < 24; i++){
    int c = i*8 + (tid >> 6), p = tid & 63;
    size_t addr = ((size_t)b*192 + c)*50176 + rem0 + p;
    xio[addr] = xio[addr] + b2f(xv[p][c]);
  }
}

// ---------- launcher ----------
extern "C" void kernel_launch(void* const* d_in, const int* in_sizes, int n_in,
                              void* d_out, int out_size, void* d_ws, size_t ws_size,
                              hipStream_t stream){
  (void)in_sizes; (void)n_in; (void)out_size; (void)ws_size;
  const float* bigx   = (const float*)d_in[0];
  const float* smx    = (const float*)d_in[1];
  const float* nw     = (const float*)d_in[2];
  const float* nb_    = (const float*)d_in[3];
  const float* qkv_w  = (const float*)d_in[4];
  const float* qkv_b  = (const float*)d_in[5];
  const float* rpb    = (const float*)d_in[6];
  const float* proj_w = (const float*)d_in[7];
  const float* proj_b = (const float*)d_in[8];
  const float* fc1_w  = (const float*)d_in[9];
  const float* fc1_b  = (const float*)d_in[10];
  const float* fc2_w  = (const float*)d_in[11];
  const float* fc2_b  = (const float*)d_in[12];

  char* ws = (char*)d_ws;
  unsigned short* wT  = (unsigned short*)ws;                    // 442368 elems (884736 B)
  unsigned short* bxn = (unsigned short*)(ws + 884736);         // 100352*192 bf16 (LN big -> Q -> attn out)
  unsigned short* xsn = (unsigned short*)(ws + 39419904);       // 25088*192 bf16
  unsigned short* kvb = (unsigned short*)(ws + 49053696);       // 25088*384 bf16
  float* xo = (float*)d_out;                                    // residual stream x, NCHW fp32

  k_wconv<<<1728, 256, 0, stream>>>(qkv_w, proj_w, fc1_w, fc2_w, wT);
  k_ln<224,14,196><<<392, 256, 0, stream>>>(bigx, nw, nb_, bxn);
  k_ln<112,7,49><<<98, 256, 0, stream>>>(smx, nw, nb_, xsn);
  // Q = bxn @ Wq + bq (in-place: each block reads only its own 64 rows before writing them)
  k_gemm_full<<<dim3(1568,1), 256, 0, stream>>>(bxn, wT, qkv_b, bxn, 192);
  // KV = xsn @ Wkv + bkv
  k_gemm_full<<<dim3(392,2), 256, 0, stream>>>(xsn, wT + 36864, qkv_b + 192, kvb, 384);
  // attention (in-place over q; disjoint row x head-col regions per block)
  k_attn<<<3072, 256, 0, stream>>>(bxn, kvb, rpb);
  // proj + bias + shortcut + window-reverse -> x (NCHW fp32 in d_out)
  k_proj_res<<<1568, 256, 0, stream>>>(bxn, wT + 110592, proj_b, bigx, xo);
  // LN -> MLP -> +residual (each block owns its 64-pixel NCHW slab; race-free)
  k_mlp<<<1568, 512, 0, stream>>>(xo, wT + 147456, fc1_b, wT + 294912, fc2_b, nw, nb_);
}